// Round 1
// baseline (234.258 us; speedup 1.0000x reference)
//
#include <hip/hip_runtime.h>
#include <hip/hip_bf16.h>

typedef __bf16 bf16_t;
typedef __bf16 bf16x8 __attribute__((ext_vector_type(8)));
typedef float f32x4 __attribute__((ext_vector_type(4)));
typedef float f32x16 __attribute__((ext_vector_type(16)));

// 16B global -> LDS DMA (wave-uniform LDS base + lane*16, per-lane global addr)
#define GLOAD_LDS16(gp, lp) __builtin_amdgcn_global_load_lds( \
    (const __attribute__((address_space(1))) void*)(gp),      \
    (__attribute__((address_space(3))) void*)(lp), 16, 0, 0)

// element index into a [rows][64] bf16 tile with T2-style XOR swizzle:
// byte ^= ((row&7)<<4)  <=>  element col ^= ((row&7)<<3)
__device__ __forceinline__ int swz64(int row, int col) {
    return row * 64 + (col ^ ((row & 7) << 3));
}

// ---------------------------------------------------------------------------
// fp32 src[R][C] -> bf16 dst[C][R]   (unchanged)
// ---------------------------------------------------------------------------
__global__ __launch_bounds__(256) void transpose_cast_kernel(
    const float* __restrict__ src, bf16_t* __restrict__ dst, int R, int C)
{
    __shared__ float tile[32][33];
    const int bx = blockIdx.x;  // C/32
    const int by = blockIdx.y;  // R/32
    const int t  = threadIdx.x;
    const int i0 = t >> 5;      // 0..7
    const int j  = t & 31;
#pragma unroll
    for (int p = 0; p < 4; ++p) {
        int i = i0 + p * 8;
        tile[i][j] = src[(long)(by * 32 + i) * C + bx * 32 + j];
    }
    __syncthreads();
#pragma unroll
    for (int p = 0; p < 4; ++p) {
        int i = i0 + p * 8;
        dst[(long)(bx * 32 + i) * R + by * 32 + j] = (bf16_t)tile[j][i];
    }
}

// ---------------------------------------------------------------------------
// QKV + window attention v2: one block per (window PAIR, head).
// 2048 blocks x 256 thr, 64 KB LDS -> 2 blocks/CU.
// QKV GEMM: M=128 (2 windows), N=192, K=512, 32x32x16 MFMA, wave grid 2x2
// (wave tile 64x96 = 2x3 frags, acc 96 VGPR). W staged via global_load_lds
// with pre-swizzled source; x staged reg->LDS with swizzled write.
// All LDS tiles: stride 64 elements + XOR swizzle (conflict-free b128 reads).
// Attention (per window, 2 waves of 32 queries each) kept on 16x16x32 MFMA.
// ---------------------------------------------------------------------------
__global__ __launch_bounds__(256, 2) void qkv_attn_kernel(
    const float*  __restrict__ x,     // [512 windows][64][512] fp32
    const bf16_t* __restrict__ wT,    // [1536][512]  (= w_qkv^T, bf16)
    bf16_t* __restrict__ ao)          // [32768][512] bf16, proj layout
{
    __shared__ bf16_t arena[32768];        // 64 KB
    bf16_t* const lX = arena;              // stage: [128][64]
    bf16_t* const lW = arena + 8192;       // stage: [192][64]

    // XCD swizzle: keep a pair's 8 head-blocks on one XCD, pairs contiguous.
    const int id   = blockIdx.x;           // 0..2047
    const int xcd  = id & 7;
    const int s    = id >> 3;              // 0..255
    const int pr   = xcd * 32 + (s >> 3);  // window pair 0..255
    const int h    = s & 7;
    const int wid0 = pr * 2;

    const float* xw = x + (long)wid0 * 64 * 512;

    const int t    = threadIdx.x;
    const int wv   = t >> 6;
    const int lane = t & 63;
    const int wm   = wv >> 1;              // row half == window index
    const int wn   = wv & 1;               // col half (GEMM) / query half (attn)
    const int l31  = lane & 31;
    const int l5   = lane >> 5;

    // attention buffers (overlay staging arena; valid after post-GEMM barrier)
    bf16_t* const lQw = arena +     0 + wm * 12288;  // [64][64]
    bf16_t* const lKw = arena +  4096 + wm * 12288;  // [64][64]
    bf16_t* const lVw = arena +  8192 + wm * 12288;  // V^T [d][k]
    bf16_t* const lPw = arena + 24576 + wm * 4096;   // [64][64]

    f32x16 acc[2][3];
#pragma unroll
    for (int mi = 0; mi < 2; ++mi)
#pragma unroll
        for (int ni = 0; ni < 3; ++ni) acc[mi][ni] = (f32x16)0.0f;

    for (int kc = 0; kc < 8; ++kc) {
        const int k0 = kc * 64;
        // stage x chunk [128][64] fp32 -> bf16, swizzled write
#pragma unroll
        for (int p = 0; p < 4; ++p) {
            const int v  = t + p * 256;     // 0..1023
            const int r  = v >> 3;
            const int sl = v & 7;
            const float* rp = xw + (long)r * 512 + k0 + sl * 8;
            f32x4 f0 = *(const f32x4*)rp;
            f32x4 f1 = *(const f32x4*)(rp + 4);
            bf16x8 o;
            o[0] = (bf16_t)f0[0]; o[1] = (bf16_t)f0[1];
            o[2] = (bf16_t)f0[2]; o[3] = (bf16_t)f0[3];
            o[4] = (bf16_t)f1[0]; o[5] = (bf16_t)f1[1];
            o[6] = (bf16_t)f1[2]; o[7] = (bf16_t)f1[3];
            *(bf16x8*)&lX[r * 64 + ((sl ^ (r & 7)) * 8)] = o;
        }
        // stage wT chunk [192][64] via global_load_lds, inverse-swizzled source
        {
            const int lsub = lane >> 3;     // row within 8-row block
            const int sl   = lane & 7;      // dest slot
#pragma unroll
            for (int j = 0; j < 6; ++j) {
                const int rb   = wv * 6 + j;        // 0..23
                const int nr   = rb * 8 + lsub;     // 0..191
                const int ch   = sl ^ (nr & 7);     // source chunk
                const int grow = ((nr >> 6) << 9) + h * 64 + (nr & 63);
                GLOAD_LDS16(wT + (long)grow * 512 + k0 + ch * 8, &lW[rb * 512]);
            }
        }
        __syncthreads();
#pragma unroll
        for (int ks = 0; ks < 64; ks += 16) {
            bf16x8 a0 = *(const bf16x8*)&lX[swz64(wm * 64 +  0 + l31, ks + l5 * 8)];
            bf16x8 a1 = *(const bf16x8*)&lX[swz64(wm * 64 + 32 + l31, ks + l5 * 8)];
#pragma unroll
            for (int ni = 0; ni < 3; ++ni) {
                bf16x8 b = *(const bf16x8*)&lW[swz64(wn * 96 + ni * 32 + l31, ks + l5 * 8)];
                acc[0][ni] = __builtin_amdgcn_mfma_f32_32x32x16_bf16(a0, b, acc[0][ni], 0, 0, 0);
                acc[1][ni] = __builtin_amdgcn_mfma_f32_32x32x16_bf16(a1, b, acc[1][ni], 0, 0, 0);
            }
        }
        __syncthreads();   // also guards arena reuse next chunk
    }

    // scatter QKV accumulators to LDS.
    // 32x32 C/D layout: col = lane&31, row = (reg&3) + 8*(reg>>2) + 4*(lane>>5)
#pragma unroll
    for (int mi = 0; mi < 2; ++mi) {
#pragma unroll
        for (int ni = 0; ni < 3; ++ni) {
            const int n = wn * 96 + ni * 32 + l31;
            const int g = n >> 6;            // 0=Q 1=K 2=V (wave-uniform)
            const int c = n & 63;
#pragma unroll
            for (int r = 0; r < 16; ++r) {
                const int tk = mi * 32 + (r & 3) + ((r >> 2) << 3) + (l5 << 2);
                const bf16_t val = (bf16_t)acc[mi][ni][r];
                if (g == 0)      lQw[swz64(tk, c)] = val;
                else if (g == 1) lKw[swz64(tk, c)] = val;
                else             lVw[swz64(c, tk)] = val;   // V transposed
            }
        }
    }
    __syncthreads();   // all QKV of both windows in LDS

    // ---- attention: wave handles window wm, queries qh..qh+31 ----
    const int lr = lane & 15;
    const int q  = lane >> 4;
    const int qh = wn * 32;
    const float scale = 0.125f;

    f32x4 sA[2][4];
#pragma unroll
    for (int i = 0; i < 2; ++i)
#pragma unroll
        for (int j = 0; j < 4; ++j) sA[i][j] = (f32x4)0.0f;
#pragma unroll
    for (int ks = 0; ks < 64; ks += 32) {
        bf16x8 aq0 = *(const bf16x8*)&lQw[swz64(qh +  0 + lr, ks + q * 8)];
        bf16x8 aq1 = *(const bf16x8*)&lQw[swz64(qh + 16 + lr, ks + q * 8)];
#pragma unroll
        for (int j = 0; j < 4; ++j) {
            bf16x8 bk = *(const bf16x8*)&lKw[swz64(j * 16 + lr, ks + q * 8)];
            sA[0][j] = __builtin_amdgcn_mfma_f32_16x16x32_bf16(aq0, bk, sA[0][j], 0, 0, 0);
            sA[1][j] = __builtin_amdgcn_mfma_f32_16x16x32_bf16(aq1, bk, sA[1][j], 0, 0, 0);
        }
    }

    // softmax: row = qh + i*16 + q*4 + reg, keys = j*16 + lr
#pragma unroll
    for (int i = 0; i < 2; ++i)
#pragma unroll
    for (int reg = 0; reg < 4; ++reg) {
        float m = fmaxf(fmaxf(sA[i][0][reg], sA[i][1][reg]),
                        fmaxf(sA[i][2][reg], sA[i][3][reg]));
#pragma unroll
        for (int d = 1; d < 16; d <<= 1) m = fmaxf(m, __shfl_xor(m, d));
        float p[4];
        float sum = 0.0f;
#pragma unroll
        for (int j = 0; j < 4; ++j) {
            p[j] = __expf((sA[i][j][reg] - m) * scale);
            sum += p[j];
        }
#pragma unroll
        for (int d = 1; d < 16; d <<= 1) sum += __shfl_xor(sum, d);
        const float inv = 1.0f / sum;
        const int row = qh + i * 16 + q * 4 + reg;
#pragma unroll
        for (int j = 0; j < 4; ++j)
            lPw[swz64(row, j * 16 + lr)] = (bf16_t)(p[j] * inv);
    }
    // lPw rows are wave-private; no barrier needed before PV.

    f32x4 o[2][4];
#pragma unroll
    for (int i = 0; i < 2; ++i)
#pragma unroll
        for (int d4 = 0; d4 < 4; ++d4) o[i][d4] = (f32x4)0.0f;
#pragma unroll
    for (int ks = 0; ks < 64; ks += 32) {
        bf16x8 ap0 = *(const bf16x8*)&lPw[swz64(qh +  0 + lr, ks + q * 8)];
        bf16x8 ap1 = *(const bf16x8*)&lPw[swz64(qh + 16 + lr, ks + q * 8)];
#pragma unroll
        for (int d4 = 0; d4 < 4; ++d4) {
            bf16x8 bv = *(const bf16x8*)&lVw[swz64(d4 * 16 + lr, ks + q * 8)];
            o[0][d4] = __builtin_amdgcn_mfma_f32_16x16x32_bf16(ap0, bv, o[0][d4], 0, 0, 0);
            o[1][d4] = __builtin_amdgcn_mfma_f32_16x16x32_bf16(ap1, bv, o[1][d4], 0, 0, 0);
        }
    }

    // ---- write O to global ao in proj-matrix coordinates ----
    const int wid = wid0 + wm;
    const int bb  = wid >> 6;
    const int nw  = wid & 63;
    bf16_t* aop = ao + ((long)bb * 4096 + (long)h * 512 + nw * 8) * 512;
#pragma unroll
    for (int i = 0; i < 2; ++i)
#pragma unroll
    for (int d4 = 0; d4 < 4; ++d4)
#pragma unroll
    for (int reg = 0; reg < 4; ++reg) {
        const int wr = qh + i * 16 + q * 4 + reg;
        aop[(long)(wr >> 3) * 512 + (wr & 7) * 64 + d4 * 16 + lr] =
            (bf16_t)o[i][d4][reg];
    }
}

// ---------------------------------------------------------------------------
// out[M,N] = ao[M,K] @ pT[N,K]^T + bias  (unchanged this round)
// ---------------------------------------------------------------------------
#define LDP 72

__global__ __launch_bounds__(256) void gemm2_kernel(
    const bf16_t* __restrict__ A,    // [M,K] = ao
    const bf16_t* __restrict__ Bt,   // [N,K] = pT
    const float*  __restrict__ bias, // [N]
    float* __restrict__ C,           // [M,N]
    int M, int N, int K)
{
    __shared__ bf16_t lA[128 * LDP];
    __shared__ bf16_t lB[128 * LDP];

    const int tid  = threadIdx.x;
    const int wave = tid >> 6;
    const int lane = tid & 63;
    const int wm   = wave >> 1;
    const int wn   = wave & 1;
    const int lr   = lane & 15;
    const int q    = lane >> 4;

    const int id  = blockIdx.x;       // 0..1023
    const int xcd = id & 7;
    const int s   = id >> 3;          // 0..127
    const int bm  = xcd * 32 + (s >> 2);
    const int bn  = s & 3;

    const long arow0 = (long)bm * 128;
    const long brow0 = (long)bn * 128;

    f32x4 acc[4][4];
#pragma unroll
    for (int i = 0; i < 4; ++i)
#pragma unroll
        for (int j = 0; j < 4; ++j) acc[i][j] = (f32x4)0.0f;

    const int srow = tid >> 3;        // 0..31
    const int scol = (tid & 7) * 8;   // 0..56

    const int nk = K / 64;
    for (int kt = 0; kt < nk; ++kt) {
        const bf16_t* Ag = A + arow0 * K + kt * 64;
        const bf16_t* Bg = Bt + brow0 * K + kt * 64;
        bf16x8 av[4], bv[4];
#pragma unroll
        for (int p = 0; p < 4; ++p) {
            const int r = srow + p * 32;
            av[p] = *(const bf16x8*)(Ag + (long)r * K + scol);
            bv[p] = *(const bf16x8*)(Bg + (long)r * K + scol);
        }
#pragma unroll
        for (int p = 0; p < 4; ++p) {
            const int r = srow + p * 32;
            *(bf16x8*)&lA[r * LDP + scol] = av[p];
            *(bf16x8*)&lB[r * LDP + scol] = bv[p];
        }
        __syncthreads();
#pragma unroll
        for (int ks = 0; ks < 64; ks += 32) {
            bf16x8 af[4], bf[4];
#pragma unroll
            for (int i = 0; i < 4; ++i)
                af[i] = *(const bf16x8*)&lA[(wm * 64 + i * 16 + lr) * LDP + ks + q * 8];
#pragma unroll
            for (int j = 0; j < 4; ++j)
                bf[j] = *(const bf16x8*)&lB[(wn * 64 + j * 16 + lr) * LDP + ks + q * 8];
#pragma unroll
            for (int i = 0; i < 4; ++i)
#pragma unroll
                for (int j = 0; j < 4; ++j)
                    acc[i][j] = __builtin_amdgcn_mfma_f32_16x16x32_bf16(
                        af[i], bf[j], acc[i][j], 0, 0, 0);
        }
        __syncthreads();
    }

#pragma unroll
    for (int i = 0; i < 4; ++i) {
        const long r = arow0 + wm * 64 + i * 16 + q * 4;
#pragma unroll
        for (int j = 0; j < 4; ++j) {
            const long c = brow0 + wn * 64 + j * 16 + lr;
            const float bv2 = bias[c];
#pragma unroll
            for (int reg = 0; reg < 4; ++reg) {
                C[(r + reg) * N + c] = acc[i][j][reg] + bv2;
            }
        }
    }
}

// ---------------------------------------------------------------------------
extern "C" void kernel_launch(void* const* d_in, const int* in_sizes, int n_in,
                              void* d_out, int out_size, void* d_ws, size_t ws_size,
                              hipStream_t stream)
{
    (void)in_sizes; (void)n_in; (void)out_size; (void)ws_size;
    const float* x     = (const float*)d_in[0];  // [8,64,64,512] fp32
    const float* wqkv  = (const float*)d_in[1];  // [512,1536] fp32
    const float* wproj = (const float*)d_in[2];  // [512,512] fp32
    const float* bproj = (const float*)d_in[3];  // [512] fp32
    float* out = (float*)d_out;                  // [8,64,64,512] fp32

    bf16_t* wT = (bf16_t*)d_ws;                  // [1536][512]
    bf16_t* pT = wT + (size_t)1536 * 512;        // [512][512]
    bf16_t* ao = pT + (size_t)512 * 512;         // [32768][512] proj layout

    transpose_cast_kernel<<<dim3(48, 16), 256, 0, stream>>>(wqkv, wT, 512, 1536);
    transpose_cast_kernel<<<dim3(16, 16), 256, 0, stream>>>(wproj, pT, 512, 512);

    qkv_attn_kernel<<<2048, 256, 0, stream>>>(x, wT, ao);

    gemm2_kernel<<<1024, 256, 0, stream>>>(
        ao, pT, bproj, out, 32768, 512, 512);
}

// Round 3
// 228.658 us; speedup vs baseline: 1.0245x; 1.0245x over previous
//
#include <hip/hip_runtime.h>
#include <hip/hip_bf16.h>

typedef __bf16 bf16_t;
typedef __bf16 bf16x8 __attribute__((ext_vector_type(8)));
typedef float f32x4 __attribute__((ext_vector_type(4)));
typedef float f32x16 __attribute__((ext_vector_type(16)));

// 16B global -> LDS DMA (wave-uniform LDS base, dest = base + lane*16)
#define GLOAD_LDS16(gp, lp) __builtin_amdgcn_global_load_lds( \
    (const __attribute__((address_space(1))) void*)(gp),      \
    (__attribute__((address_space(3))) void*)(lp), 16, 0, 0)

// element index into a [rows][64] bf16 tile with XOR swizzle:
// byte ^= ((row&7)<<4)  <=>  element col ^= ((row&7)<<3)
__device__ __forceinline__ int swz64(int row, int col) {
    return row * 64 + (col ^ ((row & 7) << 3));
}

// ---------------------------------------------------------------------------
// fp32 src[R][C] -> bf16 dst[C][R]
// ---------------------------------------------------------------------------
__global__ __launch_bounds__(256) void transpose_cast_kernel(
    const float* __restrict__ src, bf16_t* __restrict__ dst, int R, int C)
{
    __shared__ float tile[32][33];
    const int bx = blockIdx.x;  // C/32
    const int by = blockIdx.y;  // R/32
    const int t  = threadIdx.x;
    const int i0 = t >> 5;      // 0..7
    const int j  = t & 31;
#pragma unroll
    for (int p = 0; p < 4; ++p) {
        int i = i0 + p * 8;
        tile[i][j] = src[(long)(by * 32 + i) * C + bx * 32 + j];
    }
    __syncthreads();
#pragma unroll
    for (int p = 0; p < 4; ++p) {
        int i = i0 + p * 8;
        dst[(long)(bx * 32 + i) * R + by * 32 + j] = (bf16_t)tile[j][i];
    }
}

// ---------------------------------------------------------------------------
// fp32 -> bf16 cast, vectorized grid-stride (x pre-cast: done ONCE instead of
// once per head-block inside the attention kernel's K-loop).
// ---------------------------------------------------------------------------
__global__ __launch_bounds__(256) void cast_x_kernel(
    const float* __restrict__ src, bf16_t* __restrict__ dst, long n8)
{
    long i = (long)blockIdx.x * blockDim.x + threadIdx.x;
    const long stride = (long)gridDim.x * blockDim.x;
    for (; i < n8; i += stride) {
        const float* p = src + i * 8;
        f32x4 f0 = *(const f32x4*)p;
        f32x4 f1 = *(const f32x4*)(p + 4);
        bf16x8 o;
        o[0] = (bf16_t)f0[0]; o[1] = (bf16_t)f0[1];
        o[2] = (bf16_t)f0[2]; o[3] = (bf16_t)f0[3];
        o[4] = (bf16_t)f1[0]; o[5] = (bf16_t)f1[1];
        o[6] = (bf16_t)f1[2]; o[7] = (bf16_t)f1[3];
        *(bf16x8*)(dst + i * 8) = o;
    }
}

// ---------------------------------------------------------------------------
// QKV + window attention v3: one block per (window PAIR, head).
// 2048 blocks x 256 thr, 80 KB LDS -> 2 blocks/CU.
// K-loop pure-DMA, issue-early double-buffered (T14/T3 minimal recipe):
//   STAGE(kc+1 -> other buf)  [10 global_load_lds/thread, no VALU]
//   compute kc (20 ds_read_b128 + 24 MFMA 32x32x16 per wave)
//   __syncthreads  (implicit vmcnt(0): loads had the whole compute to land)
// One barrier per chunk; x read as bf16 (pre-cast).
// ---------------------------------------------------------------------------
__global__ __launch_bounds__(256, 2) void qkv_attn_kernel(
    const bf16_t* __restrict__ xb,    // [32768][512] bf16 (pre-cast x)
    const bf16_t* __restrict__ wT,    // [1536][512]  (= w_qkv^T, bf16)
    bf16_t* __restrict__ ao)          // [32768][512] bf16, proj layout
{
    __shared__ bf16_t arena[40960];        // 80 KB
    bf16_t* const buf0 = arena;            // [lX 128x64 | lW 192x64]
    bf16_t* const buf1 = arena + 20480;

    // XCD swizzle: a pair's 8 head-blocks on one XCD, pairs contiguous.
    const int id   = blockIdx.x;           // 0..2047
    const int xcd  = id & 7;
    const int s    = id >> 3;              // 0..255
    const int pr   = xcd * 32 + (s >> 3);  // window pair 0..255
    const int h    = s & 7;
    const int wid0 = pr * 2;

    const bf16_t* xw = xb + (long)wid0 * 64 * 512;

    const int t    = threadIdx.x;
    const int wv   = t >> 6;
    const int lane = t & 63;
    const int wm   = wv >> 1;              // row half == window index
    const int wn   = wv & 1;               // col half (GEMM) / query half (attn)
    const int l31  = lane & 31;
    const int l5   = lane >> 5;
    const int rlo  = lane >> 3;            // row-within-8-block
    const int ch   = (lane & 7) ^ rlo;     // pre-swizzled source chunk

    // attention overlay (valid after post-GEMM barrier)
    bf16_t* const lQw = arena +     0 + wm * 12288;  // [64][64]
    bf16_t* const lKw = arena +  4096 + wm * 12288;  // [64][64]
    bf16_t* const lVw = arena +  8192 + wm * 12288;  // V^T [d][k]
    bf16_t* const lPw = arena + 24576 + wm * 4096;   // [64][64]

    // stage chunk k0 into buf: x 16 row-blocks (4/wave), W 24 row-blocks (6/wave)
    auto stage = [&](bf16_t* buf, int k0) {
#pragma unroll
        for (int p = 0; p < 4; ++p) {
            const int rb = wv * 4 + p;                 // 0..15
            GLOAD_LDS16(xw + (long)(rb * 8 + rlo) * 512 + k0 + ch * 8,
                        buf + rb * 512);
        }
#pragma unroll
        for (int j = 0; j < 6; ++j) {
            const int rb = wv * 6 + j;                 // 0..23
            const int nr = rb * 8 + rlo;               // 0..191
            const int grow = ((nr >> 6) << 9) + h * 64 + (nr & 63);
            GLOAD_LDS16(wT + (long)grow * 512 + k0 + ch * 8,
                        buf + 8192 + rb * 512);
        }
    };

    f32x16 acc[2][3];
#pragma unroll
    for (int mi = 0; mi < 2; ++mi)
#pragma unroll
        for (int ni = 0; ni < 3; ++ni) acc[mi][ni] = (f32x16)0.0f;

    auto compute = [&](const bf16_t* lX, const bf16_t* lW) {
#pragma unroll
        for (int ks = 0; ks < 64; ks += 16) {
            bf16x8 a0 = *(const bf16x8*)&lX[swz64(wm * 64 +  0 + l31, ks + l5 * 8)];
            bf16x8 a1 = *(const bf16x8*)&lX[swz64(wm * 64 + 32 + l31, ks + l5 * 8)];
#pragma unroll
            for (int ni = 0; ni < 3; ++ni) {
                bf16x8 b = *(const bf16x8*)&lW[swz64(wn * 96 + ni * 32 + l31, ks + l5 * 8)];
                acc[0][ni] = __builtin_amdgcn_mfma_f32_32x32x16_bf16(a0, b, acc[0][ni], 0, 0, 0);
                acc[1][ni] = __builtin_amdgcn_mfma_f32_32x32x16_bf16(a1, b, acc[1][ni], 0, 0, 0);
            }
        }
    };

    // prologue
    stage(buf0, 0);
    __syncthreads();
    // main loop, explicit 2-step unroll so buffers are compile-time (rule #20)
#pragma unroll 1
    for (int kc2 = 0; kc2 < 4; ++kc2) {
        const int kc = kc2 * 2;
        stage(buf1, (kc + 1) * 64);              // kc <= 6: always stage
        compute(buf0, buf0 + 8192);
        __syncthreads();
        if (kc + 2 < 8) stage(buf0, (kc + 2) * 64);
        compute(buf1, buf1 + 8192);
        __syncthreads();
    }

    // scatter QKV accumulators to LDS.
    // 32x32 C/D layout: col = lane&31, row = (reg&3) + 8*(reg>>2) + 4*(lane>>5)
#pragma unroll
    for (int mi = 0; mi < 2; ++mi) {
#pragma unroll
        for (int ni = 0; ni < 3; ++ni) {
            const int n = wn * 96 + ni * 32 + l31;
            const int g = n >> 6;            // 0=Q 1=K 2=V (wave-uniform)
            const int c = n & 63;
#pragma unroll
            for (int r = 0; r < 16; ++r) {
                const int tk = mi * 32 + (r & 3) + ((r >> 2) << 3) + (l5 << 2);
                const bf16_t val = (bf16_t)acc[mi][ni][r];
                if (g == 0)      lQw[swz64(tk, c)] = val;
                else if (g == 1) lKw[swz64(tk, c)] = val;
                else             lVw[swz64(c, tk)] = val;   // V transposed
            }
        }
    }
    __syncthreads();   // all QKV of both windows in LDS

    // ---- attention: wave handles window wm, queries qh..qh+31 ----
    const int lr = lane & 15;
    const int q  = lane >> 4;
    const int qh = wn * 32;
    const float scale = 0.125f;

    f32x4 sA[2][4];
#pragma unroll
    for (int i = 0; i < 2; ++i)
#pragma unroll
        for (int j = 0; j < 4; ++j) sA[i][j] = (f32x4)0.0f;
#pragma unroll
    for (int ks = 0; ks < 64; ks += 32) {
        bf16x8 aq0 = *(const bf16x8*)&lQw[swz64(qh +  0 + lr, ks + q * 8)];
        bf16x8 aq1 = *(const bf16x8*)&lQw[swz64(qh + 16 + lr, ks + q * 8)];
#pragma unroll
        for (int j = 0; j < 4; ++j) {
            bf16x8 bk = *(const bf16x8*)&lKw[swz64(j * 16 + lr, ks + q * 8)];
            sA[0][j] = __builtin_amdgcn_mfma_f32_16x16x32_bf16(aq0, bk, sA[0][j], 0, 0, 0);
            sA[1][j] = __builtin_amdgcn_mfma_f32_16x16x32_bf16(aq1, bk, sA[1][j], 0, 0, 0);
        }
    }

    // softmax: row = qh + i*16 + q*4 + reg, keys = j*16 + lr
#pragma unroll
    for (int i = 0; i < 2; ++i)
#pragma unroll
    for (int reg = 0; reg < 4; ++reg) {
        float m = fmaxf(fmaxf(sA[i][0][reg], sA[i][1][reg]),
                        fmaxf(sA[i][2][reg], sA[i][3][reg]));
#pragma unroll
        for (int d = 1; d < 16; d <<= 1) m = fmaxf(m, __shfl_xor(m, d));
        float p[4];
        float sum = 0.0f;
#pragma unroll
        for (int j = 0; j < 4; ++j) {
            p[j] = __expf((sA[i][j][reg] - m) * scale);
            sum += p[j];
        }
#pragma unroll
        for (int d = 1; d < 16; d <<= 1) sum += __shfl_xor(sum, d);
        const float inv = 1.0f / sum;
        const int row = qh + i * 16 + q * 4 + reg;
#pragma unroll
        for (int j = 0; j < 4; ++j)
            lPw[swz64(row, j * 16 + lr)] = (bf16_t)(p[j] * inv);
    }
    // lPw rows are wave-private; no barrier needed before PV.

    f32x4 o[2][4];
#pragma unroll
    for (int i = 0; i < 2; ++i)
#pragma unroll
        for (int d4 = 0; d4 < 4; ++d4) o[i][d4] = (f32x4)0.0f;
#pragma unroll
    for (int ks = 0; ks < 64; ks += 32) {
        bf16x8 ap0 = *(const bf16x8*)&lPw[swz64(qh +  0 + lr, ks + q * 8)];
        bf16x8 ap1 = *(const bf16x8*)&lPw[swz64(qh + 16 + lr, ks + q * 8)];
#pragma unroll
        for (int d4 = 0; d4 < 4; ++d4) {
            bf16x8 bv = *(const bf16x8*)&lVw[swz64(d4 * 16 + lr, ks + q * 8)];
            o[0][d4] = __builtin_amdgcn_mfma_f32_16x16x32_bf16(ap0, bv, o[0][d4], 0, 0, 0);
            o[1][d4] = __builtin_amdgcn_mfma_f32_16x16x32_bf16(ap1, bv, o[1][d4], 0, 0, 0);
        }
    }

    // ---- write O to global ao in proj-matrix coordinates ----
    const int wid = wid0 + wm;
    const int bb  = wid >> 6;
    const int nw  = wid & 63;
    bf16_t* aop = ao + ((long)bb * 4096 + (long)h * 512 + nw * 8) * 512;
#pragma unroll
    for (int i = 0; i < 2; ++i)
#pragma unroll
    for (int d4 = 0; d4 < 4; ++d4)
#pragma unroll
    for (int reg = 0; reg < 4; ++reg) {
        const int wr = qh + i * 16 + q * 4 + reg;
        aop[(long)(wr >> 3) * 512 + (wr & 7) * 64 + d4 * 16 + lr] =
            (bf16_t)o[i][d4][reg];
    }
}

// ---------------------------------------------------------------------------
// out[M,N] = ao[M,K] @ pT[N,K]^T + bias, m97 structure: global_load_lds
// staging (pre-swizzled source, swizzled conflict-free ds_read_b128),
// 128x128 tile, BK=64, 32 KB LDS.
// ---------------------------------------------------------------------------
__global__ __launch_bounds__(256) void gemm2_kernel(
    const bf16_t* __restrict__ A,    // [M,K] = ao
    const bf16_t* __restrict__ Bt,   // [N,K] = pT
    const float*  __restrict__ bias, // [N]
    float* __restrict__ C,           // [M,N]
    int M, int N, int K)
{
    __shared__ bf16_t lA[8192];      // [128][64] swizzled
    __shared__ bf16_t lB[8192];

    const int tid  = threadIdx.x;
    const int wave = tid >> 6;
    const int lane = tid & 63;
    const int wm   = wave >> 1;
    const int wn   = wave & 1;
    const int lr   = lane & 15;
    const int q    = lane >> 4;
    const int rlo  = lane >> 3;
    const int ch   = (lane & 7) ^ rlo;

    const int id  = blockIdx.x;       // 0..1023
    const int xcd = id & 7;
    const int s   = id >> 3;          // 0..127
    const int bm  = xcd * 32 + (s >> 2);
    const int bn  = s & 3;

    const long arow0 = (long)bm * 128;
    const long brow0 = (long)bn * 128;

    f32x4 acc[4][4];
#pragma unroll
    for (int i = 0; i < 4; ++i)
#pragma unroll
        for (int j = 0; j < 4; ++j) acc[i][j] = (f32x4)0.0f;

    const int nk = K / 64;
    for (int kt = 0; kt < nk; ++kt) {
        const long k0 = kt * 64;
#pragma unroll
        for (int p = 0; p < 4; ++p) {
            const int rb = wave * 4 + p;              // 0..15
            const int r  = rb * 8 + rlo;              // 0..127
            GLOAD_LDS16(A  + (arow0 + r) * (long)K + k0 + ch * 8, lA + rb * 512);
            GLOAD_LDS16(Bt + (brow0 + r) * (long)K + k0 + ch * 8, lB + rb * 512);
        }
        __syncthreads();
#pragma unroll
        for (int ks = 0; ks < 64; ks += 32) {
            bf16x8 af[4], bf[4];
#pragma unroll
            for (int i = 0; i < 4; ++i)
                af[i] = *(const bf16x8*)&lA[swz64(wm * 64 + i * 16 + lr, ks + q * 8)];
#pragma unroll
            for (int j = 0; j < 4; ++j)
                bf[j] = *(const bf16x8*)&lB[swz64(wn * 64 + j * 16 + lr, ks + q * 8)];
#pragma unroll
            for (int i = 0; i < 4; ++i)
#pragma unroll
                for (int j = 0; j < 4; ++j)
                    acc[i][j] = __builtin_amdgcn_mfma_f32_16x16x32_bf16(
                        af[i], bf[j], acc[i][j], 0, 0, 0);
        }
        __syncthreads();
    }

    // epilogue: C/D layout col=lane&15, row=(lane>>4)*4+reg
#pragma unroll
    for (int i = 0; i < 4; ++i) {
        const long r = arow0 + wm * 64 + i * 16 + q * 4;
#pragma unroll
        for (int j = 0; j < 4; ++j) {
            const long c = brow0 + wn * 64 + j * 16 + lr;
            const float bv2 = bias[c];
#pragma unroll
            for (int reg = 0; reg < 4; ++reg) {
                C[(r + reg) * N + c] = acc[i][j][reg] + bv2;
            }
        }
    }
}

// ---------------------------------------------------------------------------
extern "C" void kernel_launch(void* const* d_in, const int* in_sizes, int n_in,
                              void* d_out, int out_size, void* d_ws, size_t ws_size,
                              hipStream_t stream)
{
    (void)in_sizes; (void)n_in; (void)out_size;
    const float* x     = (const float*)d_in[0];  // [8,64,64,512] fp32
    const float* wqkv  = (const float*)d_in[1];  // [512,1536] fp32
    const float* wproj = (const float*)d_in[2];  // [512,512] fp32
    const float* bproj = (const float*)d_in[3];  // [512] fp32
    float* out = (float*)d_out;                  // [8,64,64,512] fp32

    // workspace: wT 1.5 MB + pT 0.5 MB + ao 32 MB (+ xb 32 MB when it fits)
    bf16_t* wT = (bf16_t*)d_ws;                  // [1536][512]
    bf16_t* pT = wT + (size_t)1536 * 512;        // [512][512]
    bf16_t* ao = pT + (size_t)512 * 512;         // [32768][512] proj layout

    // x pre-cast scratch: prefer workspace; fall back to d_out's first 32 MB
    // (fully overwritten by gemm2 afterwards, stream-ordered).
    const size_t base_elems = (size_t)1536 * 512 + (size_t)512 * 512
                            + (size_t)32768 * 512;
    const size_t xb_elems   = (size_t)32768 * 512;
    bf16_t* xb = (ws_size >= (base_elems + xb_elems) * sizeof(bf16_t))
               ? (ao + xb_elems)
               : (bf16_t*)d_out;

    transpose_cast_kernel<<<dim3(48, 16), 256, 0, stream>>>(wqkv, wT, 512, 1536);
    transpose_cast_kernel<<<dim3(16, 16), 256, 0, stream>>>(wproj, pT, 512, 512);
    cast_x_kernel<<<2048, 256, 0, stream>>>(x, xb, (long)32768 * 512 / 8);

    qkv_attn_kernel<<<2048, 256, 0, stream>>>(xb, wT, ao);

    gemm2_kernel<<<1024, 256, 0, stream>>>(
        ao, pT, bproj, out, 32768, 512, 512);
}